// Round 1
// 739.392 us; speedup vs baseline: 1.1243x; 1.1243x over previous
//
#include <hip/hip_runtime.h>
#include <hip/hip_bf16.h>

// HRR self-attention, real-arithmetic + Hermitian-packed restructure (round 4):
//   qkv = x @ [Wq;Wkv]^T  (bf16 MFMA GEMM, per-head L2-normalize fused; Parseval)
//   F   = qkv_rows(2R x 128) @ CSp^T  (packed rDFT-128 as GEMM, out 2R x 128)
//   freq-domain causal cumsum of KF + complex mult -> QV (67 MB, packed)
//   out = QV_flat @ Wo2^T  where Wo2 = Wo (.) blockdiag-iDFT  (folded on device)
// Round 4: the two big GEMMs (qkv, out) moved from the m97 128^2 2-barrier
// structure (~830 TF ceiling) to the 256^2 8-phase counted-vmcnt template
// (T1 XCD swizzle + T2 LDS XOR swizzle + T3/T4 8-phase counted vmcnt + T5
// setprio). rDFT (N=128) and fold GEMM stay on the old 128^2 kernel.

typedef unsigned short u16;
typedef unsigned int u32;
typedef __attribute__((ext_vector_type(8))) short short8;
typedef __attribute__((ext_vector_type(4))) float f32x4;

__device__ __forceinline__ float bf2f(u16 u) {
  u32 x = ((u32)u) << 16;
  float f; __builtin_memcpy(&f, &x, 4); return f;
}
__device__ __forceinline__ u16 f2bf(float f) {
  __hip_bfloat16 h = __float2bfloat16(f);
  u16 u; __builtin_memcpy(&u, &h, 2); return u;
}
__device__ __forceinline__ u32 pack2(float a, float b) {
  return (u32)f2bf(a) | ((u32)f2bf(b) << 16);
}

#define GLD16(gp, lp)                                                        \
  __builtin_amdgcn_global_load_lds(                                          \
      (const __attribute__((address_space(1))) void*)(gp),                   \
      (__attribute__((address_space(3))) void*)(lp), 16, 0, 0)

// raw barrier (no vmcnt(0) drain, unlike __syncthreads) + compiler fences
#define BARX()                                                               \
  do {                                                                       \
    asm volatile("" ::: "memory");                                           \
    __builtin_amdgcn_s_barrier();                                            \
    asm volatile("" ::: "memory");                                           \
  } while (0)

// ================= 256x256 8-phase bf16 GEMM: C = A(MxK) @ B(NxK)^T =========
// 512 thr = 8 waves (2M x 4N), per-wave 128x64 out, BK=64, LDS 128 KiB dbuf.
// LDS XOR swizzle: byte ^= ((byte>>8)&3)<<5 within each [row][64] bf16 tile
// (row bits 1-2 -> byte bits 5-6). global_load_lds writes linearly, so the
// swizzle is applied to the per-lane GLOBAL source address; ds_reads apply
// the same involution. Counted vmcnt(4) only at K-tile boundaries:
//   prologue: stage A(0),B(0),B(1);  tile u stages Ah0/Ah1(u+1) at phases 0/1
//   (their region in buf[(u+1)&1] was last read at tile u-1 phase 2) and
//   Bh0/Bh1(u+2) at phases 2/3 (B region of buf[u&1] free after phase 1).
//   At each boundary vmcnt(4) retires everything up through A(u+1) (B(u+1)
//   was issued even earlier), leaving only B(u+2)'s 4 loads in flight.
// EPI: 0 = fp32 out; 2 = bf16 out + per-128col-head Parseval normalize.
template <int EPI>
__global__ __launch_bounds__(512, 2) void gemm256(
    const u16* __restrict__ A, const u16* __restrict__ B, void* __restrict__ C,
    int N, int K) {
  __shared__ alignas(1024) char smem[131072];
  const int NT = K >> 6;            // K-tiles of 64 (requires K>=128, K%64==0)
  const int ntn = N >> 8;
  const int nwg = gridDim.x;
  int wg = blockIdx.x;
  wg = (wg & 7) * (nwg >> 3) + (wg >> 3);   // XCD swizzle (nwg % 8 == 0)
  const int bm = wg / ntn, bn = wg % ntn;
  const long rowBase = (long)bm << 8, colBase = (long)bn << 8;

  const int tid = threadIdx.x;
  const int w = tid >> 6, lane = tid & 63;
  const int quad = lane >> 4, l16 = lane & 15;
  const int wm = w >> 2, wn = w & 3;

  // ---- staging addressing: linear LDS dest, pre-swizzled global source ----
  // dest byte within tile D = h*16384 + r*8192 + w*1024 + lane*16
  //   -> row = D>>7, col_el = ((lane&7)*8) ^ (quad<<4)   (bits 8-9 of D = quad)
  const int grow = w * 8 + (lane >> 3);
  const int gcol = ((lane & 7) * 8) ^ ((lane >> 4) << 4);
  const u16* pa[2][2];
  const u16* pb[2][2];
#pragma unroll
  for (int h = 0; h < 2; h++)
#pragma unroll
    for (int r = 0; r < 2; r++) {
      pa[h][r] = A + (rowBase + h * 128 + r * 64 + grow) * (long)K + gcol;
      pb[h][r] = B + (colBase + h * 128 + r * 64 + grow) * (long)K + gcol;
    }
  char* ldsA = smem;            // [2 buf][256][64] bf16 = 64 KiB
  char* ldsB = smem + 65536;    // same

#define STG_A(v, h)                                                          \
  do {                                                                       \
    char* d_ = ldsA + (((v)&1) << 15) + ((h) << 14) + (w << 10);             \
    GLD16(pa[h][0] + (long)(v) * 64, d_);                                    \
    GLD16(pa[h][1] + (long)(v) * 64, d_ + 8192);                             \
  } while (0)
#define STG_B(v, h)                                                          \
  do {                                                                       \
    char* d_ = ldsB + (((v)&1) << 15) + ((h) << 14) + (w << 10);             \
    GLD16(pb[h][0] + (long)(v) * 64, d_);                                    \
    GLD16(pb[h][1] + (long)(v) * 64, d_ + 8192);                             \
  } while (0)

  // ---- fragment read addressing (swizzled) ----
  // frag (row, kstep k, quad): byte = row*128 + k*64 + quad*16, then
  // ^ ((row bits 1-2)<<5); row bits 1-2 == l16 bits 1-2 for all frags.
  const int cb0 = (quad << 4) ^ (((l16 >> 1) & 3) << 5);
  const int cb1 = cb0 ^ 64;
  const char* rdA = ldsA + (wm * 128 + l16) * 128;
  const char* rdB = ldsB + (wn * 64 + l16) * 128;

  short8 a_[8], bl[4], bh[4];
  f32x4 acc[8][4] = {};

  // ---- prologue: A(0), B(0), B(1); keep B(1) (4 loads) in flight ----
  STG_A(0, 0); STG_A(0, 1); STG_B(0, 0); STG_B(0, 1);
  STG_B(1, 0); STG_B(1, 1);
  asm volatile("s_waitcnt vmcnt(4)" ::: "memory");
  BARX();

#define PH_TOP(U)                                                            \
  const char* ab = rdA + (((U)&1) << 15);                                    \
  const char* bb = rdB + (((U)&1) << 15);

  // phase 0: read aLo(8) + bLo(4); stage Ah0(u+1); MFMA Q0 = i0-3 x j0-1
#define PH0(U, SA_)                                                          \
  do {                                                                       \
    PH_TOP(U)                                                                \
    _Pragma("unroll") for (int i = 0; i < 4; i++) {                          \
      a_[2*i]   = *(const short8*)(ab + i * 2048 + cb0);                     \
      a_[2*i+1] = *(const short8*)(ab + i * 2048 + cb1);                     \
    }                                                                        \
    _Pragma("unroll") for (int j = 0; j < 2; j++) {                          \
      bl[2*j]   = *(const short8*)(bb + j * 2048 + cb0);                     \
      bl[2*j+1] = *(const short8*)(bb + j * 2048 + cb1);                     \
    }                                                                        \
    if (SA_) STG_A((U) + 1, 0);                                              \
    BARX();                                                                  \
    __builtin_amdgcn_s_setprio(1);                                           \
    _Pragma("unroll") for (int i = 0; i < 4; i++)                            \
      _Pragma("unroll") for (int j = 0; j < 2; j++) {                        \
        acc[i][j] = __builtin_amdgcn_mfma_f32_16x16x32_bf16(a_[2*i],   bl[2*j],   acc[i][j], 0, 0, 0); \
        acc[i][j] = __builtin_amdgcn_mfma_f32_16x16x32_bf16(a_[2*i+1], bl[2*j+1], acc[i][j], 0, 0, 0); \
      }                                                                      \
    __builtin_amdgcn_s_setprio(0);                                           \
    BARX();                                                                  \
  } while (0)

  // phase 1: read bHi(4); stage Ah1(u+1); MFMA Q1 = i0-3 x j2-3
#define PH1(U, SA_)                                                          \
  do {                                                                       \
    PH_TOP(U)                                                                \
    _Pragma("unroll") for (int j = 0; j < 2; j++) {                          \
      bh[2*j]   = *(const short8*)(bb + (j + 2) * 2048 + cb0);               \
      bh[2*j+1] = *(const short8*)(bb + (j + 2) * 2048 + cb1);               \
    }                                                                        \
    if (SA_) STG_A((U) + 1, 1);                                              \
    BARX();                                                                  \
    __builtin_amdgcn_s_setprio(1);                                           \
    _Pragma("unroll") for (int i = 0; i < 4; i++)                            \
      _Pragma("unroll") for (int j = 0; j < 2; j++) {                        \
        acc[i][j+2] = __builtin_amdgcn_mfma_f32_16x16x32_bf16(a_[2*i],   bh[2*j],   acc[i][j+2], 0, 0, 0); \
        acc[i][j+2] = __builtin_amdgcn_mfma_f32_16x16x32_bf16(a_[2*i+1], bh[2*j+1], acc[i][j+2], 0, 0, 0); \
      }                                                                      \
    __builtin_amdgcn_s_setprio(0);                                           \
    BARX();                                                                  \
  } while (0)

  // phase 2: read aHi(8) (reuse a_); stage Bh0(u+2); MFMA Q2 = i4-7 x j0-1
#define PH2(U, SB_)                                                          \
  do {                                                                       \
    PH_TOP(U)                                                                \
    _Pragma("unroll") for (int i = 0; i < 4; i++) {                          \
      a_[2*i]   = *(const short8*)(ab + (i + 4) * 2048 + cb0);               \
      a_[2*i+1] = *(const short8*)(ab + (i + 4) * 2048 + cb1);               \
    }                                                                        \
    if (SB_) STG_B((U) + 2, 0);                                              \
    BARX();                                                                  \
    __builtin_amdgcn_s_setprio(1);                                           \
    _Pragma("unroll") for (int i = 0; i < 4; i++)                            \
      _Pragma("unroll") for (int j = 0; j < 2; j++) {                        \
        acc[i+4][j] = __builtin_amdgcn_mfma_f32_16x16x32_bf16(a_[2*i],   bl[2*j],   acc[i+4][j], 0, 0, 0); \
        acc[i+4][j] = __builtin_amdgcn_mfma_f32_16x16x32_bf16(a_[2*i+1], bl[2*j+1], acc[i+4][j], 0, 0, 0); \
      }                                                                      \
    __builtin_amdgcn_s_setprio(0);                                           \
    BARX();                                                                  \
  } while (0)

  // phase 3: stage Bh1(u+2); MFMA Q3 = i4-7 x j2-3; boundary vmcnt
#define PH3(U, SB_, WAITSTMT)                                                \
  do {                                                                       \
    if (SB_) STG_B((U) + 2, 1);                                              \
    BARX();                                                                  \
    __builtin_amdgcn_s_setprio(1);                                           \
    _Pragma("unroll") for (int i = 0; i < 4; i++)                            \
      _Pragma("unroll") for (int j = 0; j < 2; j++) {                        \
        acc[i+4][j+2] = __builtin_amdgcn_mfma_f32_16x16x32_bf16(a_[2*i],   bh[2*j],   acc[i+4][j+2], 0, 0, 0); \
        acc[i+4][j+2] = __builtin_amdgcn_mfma_f32_16x16x32_bf16(a_[2*i+1], bh[2*j+1], acc[i+4][j+2], 0, 0, 0); \
      }                                                                      \
    __builtin_amdgcn_s_setprio(0);                                           \
    WAITSTMT;                                                                \
    BARX();                                                                  \
  } while (0)

  for (int u = 0; u < NT - 2; ++u) {
    PH0(u, true); PH1(u, true); PH2(u, true);
    PH3(u, true, asm volatile("s_waitcnt vmcnt(4)" ::: "memory"));
  }
  {
    const int u = NT - 2;
    PH0(u, true); PH1(u, true); PH2(u, false);
    PH3(u, false, asm volatile("s_waitcnt vmcnt(0)" ::: "memory"));
  }
  {
    const int u = NT - 1;
    PH0(u, false); PH1(u, false); PH2(u, false);
    PH3(u, false, (void)0);
  }
#undef PH0
#undef PH1
#undef PH2
#undef PH3
#undef PH_TOP
#undef STG_A
#undef STG_B

  // ---- epilogue ----
  float scl[8][4];
#pragma unroll
  for (int i = 0; i < 8; i++)
#pragma unroll
    for (int r = 0; r < 4; r++) scl[i][r] = 1.0f;

  if (EPI == 2) {
    // per-head (128-col) Parseval normalize; wn pairs (0,1) and (2,3) share a
    // head; cross-wave reduce through LDS (reuse smem, pipeline is drained).
    float* ssb = (float*)smem;  // [256 rows][4 wn]
#pragma unroll
    for (int i = 0; i < 8; i++)
#pragma unroll
      for (int r = 0; r < 4; r++) {
        float s = 0.f;
#pragma unroll
        for (int j = 0; j < 4; j++) { float v = acc[i][j][r]; s += v * v; }
        s += __shfl_xor(s, 1); s += __shfl_xor(s, 2);
        s += __shfl_xor(s, 4); s += __shfl_xor(s, 8);
        if (l16 == 0) ssb[((wm * 128 + i * 16 + quad * 4 + r) << 2) + wn] = s;
      }
    __syncthreads();
#pragma unroll
    for (int i = 0; i < 8; i++)
#pragma unroll
      for (int r = 0; r < 4; r++) {
        int row = wm * 128 + i * 16 + quad * 4 + r;
        float s = ssb[(row << 2) + (wn & 2)] + ssb[(row << 2) + (wn & 2) + 1];
        scl[i][r] = rsqrtf(128.0f * s);
      }
  }

  // C/D layout: col = lane&15, row = (lane>>4)*4 + reg  [verified m89/m91]
#pragma unroll
  for (int i = 0; i < 8; i++) {
#pragma unroll
    for (int j = 0; j < 4; j++) {
      long row0 = rowBase + wm * 128 + i * 16 + quad * 4;
      long col = colBase + wn * 64 + j * 16 + l16;
#pragma unroll
      for (int r = 0; r < 4; r++) {
        float v = acc[i][j][r] * scl[i][r];
        long off = (row0 + r) * (long)N + col;
        if (EPI == 0) ((float*)C)[off] = v;
        else          ((u16*)C)[off] = f2bf(v);
      }
    }
  }
}

// ---------------- bf16 GEMM (m97 128^2): C(MxN) = A(MxK) @ B(NxK)^T --------
// kept for the rDFT (N=128) and the small iDFT-fold GEMM.
template <int EPI, bool FOLD>
__global__ __launch_bounds__(256, 2) void gemm_bt(
    const u16* __restrict__ A, const u16* __restrict__ B, void* __restrict__ C,
    int M, int N, int K, int lda) {
  const int ntiles = N >> 7;
  const int bid = blockIdx.x;
  const int bm = bid / ntiles, bn = bid % ntiles;
  const long rowBase = (long)bm * 128, colBase = (long)bn * 128;
  const long aOff = FOLD ? colBase : 0;
  const long bRowBase = FOLD ? 0 : colBase;

  __shared__ u16 As[128 * 32];  // unpadded: global_load_lds needs lane-contig dest
  __shared__ u16 Bs[128 * 32];
  __shared__ float ssbuf[128][2];

  const int tid = threadIdx.x;
  const int wave = tid >> 6, lane = tid & 63;
  const int quad = lane >> 4, l16 = lane & 15;
  const int waveRow = (wave >> 1) * 64, waveCol = (wave & 1) * 64;

  const int srow = lane >> 2, scol = (lane & 3) * 8;
  const u16* pa = A + (rowBase + wave * 32 + srow) * (long)lda + aOff + scol;
  const u16* pb = B + (bRowBase + wave * 32 + srow) * (long)K + scol;
  u16* lA0 = &As[(wave * 32) * 32];
  u16* lA1 = &As[(wave * 32 + 16) * 32];
  u16* lB0 = &Bs[(wave * 32) * 32];
  u16* lB1 = &Bs[(wave * 32 + 16) * 32];

  f32x4 acc[4][4] = {};

  for (int kt = 0; kt < K; kt += 32) {
    GLD16(pa + kt, lA0);
    GLD16(pa + kt + 16 * (long)lda, lA1);
    GLD16(pb + kt, lB0);
    GLD16(pb + kt + 16 * (long)K, lB1);
    __syncthreads();

    short8 af[4], bfr[4];
#pragma unroll
    for (int i = 0; i < 4; i++)
      af[i] = *(const short8*)&As[(waveRow + i * 16 + l16) * 32 + quad * 8];
#pragma unroll
    for (int j = 0; j < 4; j++)
      bfr[j] = *(const short8*)&Bs[(waveCol + j * 16 + l16) * 32 + quad * 8];
#pragma unroll
    for (int i = 0; i < 4; i++)
#pragma unroll
      for (int j = 0; j < 4; j++)
        acc[i][j] = __builtin_amdgcn_mfma_f32_16x16x32_bf16(af[i], bfr[j], acc[i][j], 0, 0, 0);
    __syncthreads();
  }

  float scl[4][4];
#pragma unroll
  for (int i = 0; i < 4; i++)
#pragma unroll
    for (int r = 0; r < 4; r++) scl[i][r] = 1.0f;

  if (EPI == 2) {
#pragma unroll
    for (int i = 0; i < 4; i++) {
#pragma unroll
      for (int r = 0; r < 4; r++) {
        float s = 0.f;
#pragma unroll
        for (int j = 0; j < 4; j++) { float v = acc[i][j][r]; s += v * v; }
#pragma unroll
        for (int m = 1; m < 16; m <<= 1) s += __shfl_xor(s, m);
        if (l16 == 0) ssbuf[waveRow + i * 16 + quad * 4 + r][wave & 1] = s;
      }
    }
    __syncthreads();
#pragma unroll
    for (int i = 0; i < 4; i++)
#pragma unroll
      for (int r = 0; r < 4; r++) {
        int row = waveRow + i * 16 + quad * 4 + r;
        scl[i][r] = rsqrtf(128.0f * (ssbuf[row][0] + ssbuf[row][1]));
      }
  }

#pragma unroll
  for (int i = 0; i < 4; i++) {
#pragma unroll
    for (int j = 0; j < 4; j++) {
      long row0 = rowBase + waveRow + i * 16 + quad * 4;
      long col = colBase + waveCol + j * 16 + l16;
#pragma unroll
      for (int r = 0; r < 4; r++) {
        float v = acc[i][j][r] * scl[i][r];
        long off = (row0 + r) * (long)N + col;
        if (EPI == 0) ((float*)C)[off] = v;
        else          ((u16*)C)[off] = f2bf(v);
      }
    }
  }
}

// ---------------- fp32 -> bf16 cast (vectorized x4) ----------------
__global__ __launch_bounds__(256) void cast_f2b(const float* __restrict__ in,
                                                u16* __restrict__ out, int n4) {
  int i = blockIdx.x * 256 + threadIdx.x;
  if (i >= n4) return;
  float4 v = ((const float4*)in)[i];
  ushort4 u;
  u.x = f2bf(v.x); u.y = f2bf(v.y); u.z = f2bf(v.z); u.w = f2bf(v.w);
  ((ushort4*)out)[i] = u;
}

// ---------------- packed-rDFT matrices (bf16) ----------------
__global__ __launch_bounds__(256) void init_mats(u16* __restrict__ CSp,
                                                 u16* __restrict__ W2pT) {
  int idx = blockIdx.x * 256 + threadIdx.x;  // [0, 32768)
  const float PI64 = 3.14159265358979323846f / 64.0f;
  if (idx < 16384) {
    int p = idx >> 7, n = idx & 127;
    int k = p >> 1;
    float v;
    if (p == 1) v = (n & 1) ? -1.f : 1.f;
    else {
      int t = (k * n) & 127;
      float ang = (float)t * PI64;
      v = (p & 1) ? -sinf(ang) : cosf(ang);
    }
    CSp[p * 128 + n] = f2bf(v);
  } else {
    int r = idx - 16384;
    int p = r >> 7, d = r & 127;
    int k = p >> 1;
    float v;
    if (p == 0) v = 1.0f / 128.0f;
    else if (p == 1) v = ((d & 1) ? -1.f : 1.f) / 128.0f;
    else {
      int t = (k * d) & 127;
      float ang = (float)t * PI64;
      v = ((p & 1) ? -2.f * sinf(ang) : 2.f * cosf(ang)) / 128.0f;
    }
    W2pT[p * 128 + d] = f2bf(v);
  }
}

// ---------------- freq-domain causal cumsum (chunked scan, packed rows) -----
__global__ __launch_bounds__(64) void scan_chunksum(const u16* __restrict__ F,
                                                    float* __restrict__ part) {
  int blk = blockIdx.x;          // bh*64 + c
  int c = blk & 63, bh = blk >> 6;
  int h = bh & 15, b = bh >> 4;
  int l = threadIdx.x;           // 0..63
  float s0 = 0.f, s1 = 0.f;
  for (int t = c * 64; t < c * 64 + 64; ++t) {
    u32 u = ((const u32*)(F + ((long)(b * 4096 + t) * 32 + 16 + h) * 128))[l];
    s0 += bf2f((u16)(u & 0xffff));
    s1 += bf2f((u16)(u >> 16));
  }
  float2 w; w.x = s0; w.y = s1;
  ((float2*)part)[(long)blk * 64 + l] = w;
}

__global__ __launch_bounds__(128) void scan_exclusive(float* __restrict__ part) {
  int bh = blockIdx.x;   // 0..63
  int j = threadIdx.x;   // slot 0..127
  float run = 0.f;
  for (int c = 0; c < 64; ++c) {
    long idx = ((long)(bh * 64 + c)) * 128 + j;
    float v = part[idx];
    part[idx] = run;
    run += v;
  }
}

__global__ __launch_bounds__(64) void scan_main(const u16* __restrict__ F,
                                                u16* __restrict__ QV,
                                                const float* __restrict__ part) {
  int blk = blockIdx.x;          // bh*64 + c
  int c = blk & 63, bh = blk >> 6;
  int h = bh & 15, b = bh >> 4;
  int l = threadIdx.x;           // bin l
  float2 cc = ((const float2*)part)[(long)blk * 64 + l];
  float cr = cc.x, ci = cc.y;
  for (int t = c * 64; t < c * 64 + 64; ++t) {
    long m = (long)(b * 4096 + t);
    u32 ku = ((const u32*)(F + (m * 32 + 16 + h) * 128))[l];
    u32 qu = ((const u32*)(F + (m * 32 + h) * 128))[l];
    float kr = bf2f((u16)(ku & 0xffff)), ki = bf2f((u16)(ku >> 16));
    float qr = bf2f((u16)(qu & 0xffff)), qi = bf2f((u16)(qu >> 16));
    cr += kr; ci += ki;
    float vr, vi;
    if (l == 0) { vr = qr * cr; vi = qi * ci; }  // bins 0 and 64: pure real
    else { vr = qr * cr - qi * ci; vi = qr * ci + qi * cr; }
    ((u32*)(QV + (m * 16 + h) * 128))[l] = pack2(vr, vi);
  }
}

extern "C" void kernel_launch(void* const* d_in, const int* in_sizes, int n_in,
                              void* d_out, int out_size, void* d_ws, size_t ws_size,
                              hipStream_t stream) {
  const float* x   = (const float*)d_in[0];
  const float* Wq  = (const float*)d_in[1];
  const float* Wkv = (const float*)d_in[2];
  const float* Wo  = (const float*)d_in[3];
  float* out = (float*)d_out;

  const long M1 = 16384;          // B*S
  const long D = 2048;
  const long R = M1 * 16;         // 262144 head-rows
  const long XE = M1 * D;
  const long WE = D * D;

  char* ws = (char*)d_ws;
  u16* qkh  = (u16*)(ws);                         // 134 MB: GEMM1 out; QV reuses it
  u16* F    = (u16*)(ws + 134217728);             // 134 MB: packed DFT out (2R x 128)
  u16* xb   = (u16*)(ws + 268435456);             // 67 MB
  u16* wqkb = (u16*)(ws + 335544320);             // 16.8 MB: [Wq;Wkv]
  u16* wob  = (u16*)(ws + 352321536);             // 8.4 MB
  u16* wo2  = (u16*)(ws + 360710144);             // 8.4 MB: folded iDFT.Wo
  u16* CSp  = (u16*)(ws + 369098752);             // 32 KB
  u16* W2pT = (u16*)(ws + 369131520);             // 32 KB
  float* part = (float*)(ws + 369164288);         // 2 MB (64*64*128 f32)
  u16* QV = qkh;

  // casts + transform matrices
  cast_f2b<<<(int)(XE / 4 / 256), 256, 0, stream>>>(x, xb, (int)(XE / 4));
  cast_f2b<<<(int)(WE / 4 / 256), 256, 0, stream>>>(Wq, wqkb, (int)(WE / 4));
  cast_f2b<<<(int)(WE / 4 / 256), 256, 0, stream>>>(Wkv, wqkb + WE, (int)(WE / 4));
  cast_f2b<<<(int)(WE / 4 / 256), 256, 0, stream>>>(Wo, wob, (int)(WE / 4));
  init_mats<<<128, 256, 0, stream>>>(CSp, W2pT);

  // fold iDFT into Wo:  Wo2_h = Wo_h @ W2p  (block-diagonal, M=2048,N=2048,K=128)
  gemm_bt<1, true><<<16 * 16, 256, 0, stream>>>(wob, W2pT, wo2, 2048, 2048, 128, 2048);

  // qkv = x @ [Wq;Wkv]^T, fused per-head normalize (M=16384,N=4096,K=2048)
  // 256^2 8-phase: grid 64x16 = 1024 (%8==0 for XCD swizzle)
  gemm256<2><<<(int)((M1 / 256) * (4096 / 256)), 512, 0, stream>>>(
      xb, wqkb, qkh, 4096, (int)D);

  // packed rDFT: F = qkv_rows @ CSp^T  (M=2R, N=128, K=128)
  gemm_bt<1, false><<<(int)(2 * R / 128), 256, 0, stream>>>(
      qkh, CSp, F, (int)(2 * R), 128, 128, 128);

  // chunked causal cumsum + complex multiply -> QV (packed, into qkh)
  scan_chunksum<<<64 * 64, 64, 0, stream>>>(F, part);
  scan_exclusive<<<64, 128, 0, stream>>>(part);
  scan_main<<<64 * 64, 64, 0, stream>>>(F, QV, part);

  // out = QV_flat @ Wo2^T  (fp32 out, M=16384,N=2048,K=2048; iDFT folded in)
  // 256^2 8-phase: grid 64x8 = 512 (%8==0)
  gemm256<0><<<(int)((M1 / 256) * (D / 256)), 512, 0, stream>>>(
      QV, wo2, out, (int)D, (int)D);
}

// Round 2
// 734.395 us; speedup vs baseline: 1.1320x; 1.0068x over previous
//
#include <hip/hip_runtime.h>
#include <hip/hip_bf16.h>

// HRR self-attention, real-arithmetic + Hermitian-packed restructure (round 5):
//   qkv = x @ [Wq;Wkv]^T  (bf16 MFMA GEMM, per-head L2-normalize fused; Parseval)
//   F   = qkv_rows(2R x 128) @ CSp^T  (packed rDFT-128 as GEMM, out 2R x 128)
//   freq-domain causal cumsum of KF + complex mult -> QV (67 MB, packed)
//   out = QV_flat @ Wo2^T  where Wo2 = Wo (.) blockdiag-iDFT  (folded on device)
// Round 5: gemm256 hot loop made clobber-free. Round 4 wrapped every s_barrier
// in asm volatile(""' :::"memory"), which makes LLVM's waitcnt pass drain
// vmcnt(0) at EVERY barrier (8x per K-tile) -- re-creating the m97 drain
// disease and collapsing the counted-vmcnt pipeline (observed 43.7% MfmaUtil
// vs the template's 62%). Now: raw s_barrier builtin, fragment loads as
// volatile inline-asm ds_read_b128 (invisible to the waitcnt pass; ordered
// vs barriers by volatile-volatile), explicit lgkmcnt(0)+sched_barrier(0)
// before each MFMA cluster (rule #18), counted vmcnt(4) as the only vmem wait.

typedef unsigned short u16;
typedef unsigned int u32;
typedef __attribute__((ext_vector_type(8))) short short8;
typedef __attribute__((ext_vector_type(4))) float f32x4;

__device__ __forceinline__ float bf2f(u16 u) {
  u32 x = ((u32)u) << 16;
  float f; __builtin_memcpy(&f, &x, 4); return f;
}
__device__ __forceinline__ u16 f2bf(float f) {
  __hip_bfloat16 h = __float2bfloat16(f);
  u16 u; __builtin_memcpy(&u, &h, 2); return u;
}
__device__ __forceinline__ u32 pack2(float a, float b) {
  return (u32)f2bf(a) | ((u32)f2bf(b) << 16);
}

#define GLD16(gp, lp)                                                        \
  __builtin_amdgcn_global_load_lds(                                          \
      (const __attribute__((address_space(1))) void*)(gp),                   \
      (__attribute__((address_space(3))) void*)(lp), 16, 0, 0)

// LDS byte offset of a generic pointer derived from __shared__
__device__ __forceinline__ unsigned ldsoff(const void* p) {
  return (unsigned)(size_t)(const __attribute__((address_space(3))) char*)p;
}

// volatile asm ds_read_b128: invisible to the compiler's waitcnt/alias
// machinery (no memory clobber). Ordering vs barriers/waitcnts comes from
// volatile-asm program order; data readiness is handled manually via
// s_waitcnt lgkmcnt(0) + sched_barrier(0) before the consuming MFMAs.
#define DSR(dst, ad, im)                                                     \
  asm volatile("ds_read_b128 %0, %1 offset:%c2"                              \
               : "=v"(dst) : "v"(ad), "i"(im))

#define MFMA_PRE()                                                           \
  __builtin_amdgcn_s_barrier();                                              \
  asm volatile("s_waitcnt lgkmcnt(0)");                                      \
  __builtin_amdgcn_sched_barrier(0);                                         \
  __builtin_amdgcn_s_setprio(1)

#define MFMA_POST()                                                          \
  __builtin_amdgcn_sched_barrier(0);                                         \
  __builtin_amdgcn_s_setprio(0);                                             \
  __builtin_amdgcn_s_barrier()

// ================= 256x256 8-phase bf16 GEMM: C = A(MxK) @ B(NxK)^T =========
// 512 thr = 8 waves (2M x 4N), per-wave 128x64 out, BK=64, LDS 128 KiB dbuf.
// LDS XOR swizzle: byte ^= ((byte>>8)&3)<<5, applied as pre-swizzled global
// source (global_load_lds writes linearly) + swizzled ds_read addresses.
// Counted vmcnt(4) only at K-tile boundaries (see round-4 comment): tile u
// stages A(u+1) at phases 0/1 and B(u+2) at phases 2/3; boundary vmcnt(4)
// retires everything through A(u+1), leaving B(u+2)'s 4 loads in flight.
// EPI: 0 = fp32 out; 2 = bf16 out + per-128col-head Parseval normalize.
template <int EPI>
__global__ __launch_bounds__(512, 2) void gemm256(
    const u16* __restrict__ A, const u16* __restrict__ B, void* __restrict__ C,
    int N, int K) {
  __shared__ alignas(1024) char smem[131072];
  const int NT = K >> 6;            // K-tiles of 64 (requires K>=128, K%64==0)
  const int ntn = N >> 8;
  const int nwg = gridDim.x;
  int wg = blockIdx.x;
  wg = (wg & 7) * (nwg >> 3) + (wg >> 3);   // XCD swizzle (nwg % 8 == 0)
  const int bm = wg / ntn, bn = wg % ntn;
  const long rowBase = (long)bm << 8, colBase = (long)bn << 8;

  const int tid = threadIdx.x;
  const int w = tid >> 6, lane = tid & 63;
  const int quad = lane >> 4, l16 = lane & 15;
  const int wm = w >> 2, wn = w & 3;

  // ---- staging addressing: linear LDS dest, pre-swizzled global source ----
  const int grow = w * 8 + (lane >> 3);
  const int gcol = ((lane & 7) * 8) ^ ((lane >> 4) << 4);
  const u16* pa[2][2];
  const u16* pb[2][2];
#pragma unroll
  for (int h = 0; h < 2; h++)
#pragma unroll
    for (int r = 0; r < 2; r++) {
      pa[h][r] = A + (rowBase + h * 128 + r * 64 + grow) * (long)K + gcol;
      pb[h][r] = B + (colBase + h * 128 + r * 64 + grow) * (long)K + gcol;
    }
  char* ldsA = smem;            // [2 buf][256][64] bf16 = 64 KiB
  char* ldsB = smem + 65536;

#define STG_A(v, h)                                                          \
  do {                                                                       \
    char* d_ = ldsA + (((v)&1) << 15) + ((h) << 14) + (w << 10);             \
    GLD16(pa[h][0] + (long)(v) * 64, d_);                                    \
    GLD16(pa[h][1] + (long)(v) * 64, d_ + 8192);                             \
  } while (0)
#define STG_B(v, h)                                                          \
  do {                                                                       \
    char* d_ = ldsB + (((v)&1) << 15) + ((h) << 14) + (w << 10);             \
    GLD16(pb[h][0] + (long)(v) * 64, d_);                                    \
    GLD16(pb[h][1] + (long)(v) * 64, d_ + 8192);                             \
  } while (0)

  // ---- fragment read addressing (swizzled), 32-bit LDS byte addresses ----
  const int cb0 = (quad << 4) ^ (((l16 >> 1) & 3) << 5);
  const int cb1 = cb0 ^ 64;
  const unsigned bA0 = ldsoff(ldsA + (wm * 128 + l16) * 128) + cb0;
  const unsigned bA1 = bA0 ^ 64;
  const unsigned bB0 = ldsoff(ldsB + (wn * 64 + l16) * 128) + cb0;
  const unsigned bB1 = bB0 ^ 64;
  (void)cb1;

  short8 a_[8], bl[4], bh[4];
  f32x4 acc[8][4] = {};

  // ---- prologue: A(0), B(0), B(1); keep B(1) (4 loads) in flight ----
  STG_A(0, 0); STG_A(0, 1); STG_B(0, 0); STG_B(0, 1);
  STG_B(1, 0); STG_B(1, 1);
  asm volatile("s_waitcnt vmcnt(4)");
  __builtin_amdgcn_s_barrier();

#define RUN_TILE(uu, SA_, SB_, WAITSTMT)                                     \
  do {                                                                       \
    const unsigned bsel = ((uu) & 1) << 15;                                  \
    const unsigned aA0 = bA0 ^ bsel, aA1 = bA1 ^ bsel;                       \
    const unsigned aB0 = bB0 ^ bsel, aB1 = bB1 ^ bsel;                       \
    /* phase 0: read aLo(8)+bLo(4); stage Ah0(u+1); MFMA Q0 = i0-3 x j0-1 */ \
    _Pragma("unroll") for (int i = 0; i < 4; i++) {                          \
      DSR(a_[2*i],   aA0, i * 2048);                                         \
      DSR(a_[2*i+1], aA1, i * 2048);                                         \
    }                                                                        \
    _Pragma("unroll") for (int j = 0; j < 2; j++) {                          \
      DSR(bl[2*j],   aB0, j * 2048);                                         \
      DSR(bl[2*j+1], aB1, j * 2048);                                         \
    }                                                                        \
    if (SA_) STG_A((uu) + 1, 0);                                             \
    MFMA_PRE();                                                              \
    _Pragma("unroll") for (int i = 0; i < 4; i++)                            \
      _Pragma("unroll") for (int j = 0; j < 2; j++) {                        \
        acc[i][j] = __builtin_amdgcn_mfma_f32_16x16x32_bf16(a_[2*i],   bl[2*j],   acc[i][j], 0, 0, 0); \
        acc[i][j] = __builtin_amdgcn_mfma_f32_16x16x32_bf16(a_[2*i+1], bl[2*j+1], acc[i][j], 0, 0, 0); \
      }                                                                      \
    MFMA_POST();                                                             \
    /* phase 1: read bHi(4); stage Ah1(u+1); MFMA Q1 = i0-3 x j2-3 */        \
    _Pragma("unroll") for (int j = 0; j < 2; j++) {                          \
      DSR(bh[2*j],   aB0, (j + 2) * 2048);                                   \
      DSR(bh[2*j+1], aB1, (j + 2) * 2048);                                   \
    }                                                                        \
    if (SA_) STG_A((uu) + 1, 1);                                             \
    MFMA_PRE();                                                              \
    _Pragma("unroll") for (int i = 0; i < 4; i++)                            \
      _Pragma("unroll") for (int j = 0; j < 2; j++) {                        \
        acc[i][j+2] = __builtin_amdgcn_mfma_f32_16x16x32_bf16(a_[2*i],   bh[2*j],   acc[i][j+2], 0, 0, 0); \
        acc[i][j+2] = __builtin_amdgcn_mfma_f32_16x16x32_bf16(a_[2*i+1], bh[2*j+1], acc[i][j+2], 0, 0, 0); \
      }                                                                      \
    MFMA_POST();                                                             \
    /* phase 2: read aHi(8); stage Bh0(u+2); MFMA Q2 = i4-7 x j0-1 */        \
    _Pragma("unroll") for (int i = 0; i < 4; i++) {                          \
      DSR(a_[2*i],   aA0, (i + 4) * 2048);                                   \
      DSR(a_[2*i+1], aA1, (i + 4) * 2048);                                   \
    }                                                                        \
    if (SB_) STG_B((uu) + 2, 0);                                             \
    MFMA_PRE();                                                              \
    _Pragma("unroll") for (int i = 0; i < 4; i++)                            \
      _Pragma("unroll") for (int j = 0; j < 2; j++) {                        \
        acc[i+4][j] = __builtin_amdgcn_mfma_f32_16x16x32_bf16(a_[2*i],   bl[2*j],   acc[i+4][j], 0, 0, 0); \
        acc[i+4][j] = __builtin_amdgcn_mfma_f32_16x16x32_bf16(a_[2*i+1], bl[2*j+1], acc[i+4][j], 0, 0, 0); \
      }                                                                      \
    MFMA_POST();                                                             \
    /* phase 3: stage Bh1(u+2); MFMA Q3 = i4-7 x j2-3; boundary vmcnt */     \
    if (SB_) STG_B((uu) + 2, 1);                                             \
    MFMA_PRE();                                                              \
    _Pragma("unroll") for (int i = 0; i < 4; i++)                            \
      _Pragma("unroll") for (int j = 0; j < 2; j++) {                        \
        acc[i+4][j+2] = __builtin_amdgcn_mfma_f32_16x16x32_bf16(a_[2*i],   bh[2*j],   acc[i+4][j+2], 0, 0, 0); \
        acc[i+4][j+2] = __builtin_amdgcn_mfma_f32_16x16x32_bf16(a_[2*i+1], bh[2*j+1], acc[i+4][j+2], 0, 0, 0); \
      }                                                                      \
    __builtin_amdgcn_sched_barrier(0);                                       \
    __builtin_amdgcn_s_setprio(0);                                           \
    WAITSTMT;                                                                \
    __builtin_amdgcn_s_barrier();                                            \
  } while (0)

  for (int u = 0; u < NT - 2; ++u) {
    RUN_TILE(u, true, true, asm volatile("s_waitcnt vmcnt(4)"));
  }
  RUN_TILE(NT - 2, true, false, asm volatile("s_waitcnt vmcnt(0)"));
  RUN_TILE(NT - 1, false, false, (void)0);
#undef RUN_TILE
#undef STG_A
#undef STG_B

  // keep the GLD16 LDS writes live (asm reads are opaque) + order epilogue
  asm volatile("" ::: "memory");

  // ---- epilogue ----
  float scl[8][4];
#pragma unroll
  for (int i = 0; i < 8; i++)
#pragma unroll
    for (int r = 0; r < 4; r++) scl[i][r] = 1.0f;

  if (EPI == 2) {
    // per-head (128-col) Parseval normalize; wn pairs (0,1)/(2,3) share a
    // head; cross-wave reduce through LDS (pipeline fully drained above).
    float* ssb = (float*)smem;  // [256 rows][4 wn]
    __syncthreads();
#pragma unroll
    for (int i = 0; i < 8; i++)
#pragma unroll
      for (int r = 0; r < 4; r++) {
        float s = 0.f;
#pragma unroll
        for (int j = 0; j < 4; j++) { float v = acc[i][j][r]; s += v * v; }
        s += __shfl_xor(s, 1); s += __shfl_xor(s, 2);
        s += __shfl_xor(s, 4); s += __shfl_xor(s, 8);
        if (l16 == 0) ssb[((wm * 128 + i * 16 + quad * 4 + r) << 2) + wn] = s;
      }
    __syncthreads();
#pragma unroll
    for (int i = 0; i < 8; i++)
#pragma unroll
      for (int r = 0; r < 4; r++) {
        int row = wm * 128 + i * 16 + quad * 4 + r;
        float s = ssb[(row << 2) + (wn & 2)] + ssb[(row << 2) + (wn & 2) + 1];
        scl[i][r] = rsqrtf(128.0f * s);
      }
  }

  // C/D layout: col = lane&15, row = (lane>>4)*4 + reg  [verified m89/m91]
#pragma unroll
  for (int i = 0; i < 8; i++) {
#pragma unroll
    for (int j = 0; j < 4; j++) {
      long row0 = rowBase + wm * 128 + i * 16 + quad * 4;
      long col = colBase + wn * 64 + j * 16 + l16;
#pragma unroll
      for (int r = 0; r < 4; r++) {
        float v = acc[i][j][r] * scl[i][r];
        long off = (row0 + r) * (long)N + col;
        if (EPI == 0) ((float*)C)[off] = v;
        else          ((u16*)C)[off] = f2bf(v);
      }
    }
  }
}

// ---------------- bf16 GEMM (m97 128^2): C(MxN) = A(MxK) @ B(NxK)^T --------
// kept for the rDFT (N=128) and the small iDFT-fold GEMM.
template <int EPI, bool FOLD>
__global__ __launch_bounds__(256, 2) void gemm_bt(
    const u16* __restrict__ A, const u16* __restrict__ B, void* __restrict__ C,
    int M, int N, int K, int lda) {
  const int ntiles = N >> 7;
  const int bid = blockIdx.x;
  const int bm = bid / ntiles, bn = bid % ntiles;
  const long rowBase = (long)bm * 128, colBase = (long)bn * 128;
  const long aOff = FOLD ? colBase : 0;
  const long bRowBase = FOLD ? 0 : colBase;

  __shared__ u16 As[128 * 32];
  __shared__ u16 Bs[128 * 32];
  __shared__ float ssbuf[128][2];

  const int tid = threadIdx.x;
  const int wave = tid >> 6, lane = tid & 63;
  const int quad = lane >> 4, l16 = lane & 15;
  const int waveRow = (wave >> 1) * 64, waveCol = (wave & 1) * 64;

  const int srow = lane >> 2, scol = (lane & 3) * 8;
  const u16* pa = A + (rowBase + wave * 32 + srow) * (long)lda + aOff + scol;
  const u16* pb = B + (bRowBase + wave * 32 + srow) * (long)K + scol;
  u16* lA0 = &As[(wave * 32) * 32];
  u16* lA1 = &As[(wave * 32 + 16) * 32];
  u16* lB0 = &Bs[(wave * 32) * 32];
  u16* lB1 = &Bs[(wave * 32 + 16) * 32];

  f32x4 acc[4][4] = {};

  for (int kt = 0; kt < K; kt += 32) {
    GLD16(pa + kt, lA0);
    GLD16(pa + kt + 16 * (long)lda, lA1);
    GLD16(pb + kt, lB0);
    GLD16(pb + kt + 16 * (long)K, lB1);
    __syncthreads();

    short8 af[4], bfr[4];
#pragma unroll
    for (int i = 0; i < 4; i++)
      af[i] = *(const short8*)&As[(waveRow + i * 16 + l16) * 32 + quad * 8];
#pragma unroll
    for (int j = 0; j < 4; j++)
      bfr[j] = *(const short8*)&Bs[(waveCol + j * 16 + l16) * 32 + quad * 8];
#pragma unroll
    for (int i = 0; i < 4; i++)
#pragma unroll
      for (int j = 0; j < 4; j++)
        acc[i][j] = __builtin_amdgcn_mfma_f32_16x16x32_bf16(af[i], bfr[j], acc[i][j], 0, 0, 0);
    __syncthreads();
  }

  float scl[4][4];
#pragma unroll
  for (int i = 0; i < 4; i++)
#pragma unroll
    for (int r = 0; r < 4; r++) scl[i][r] = 1.0f;

  if (EPI == 2) {
#pragma unroll
    for (int i = 0; i < 4; i++) {
#pragma unroll
      for (int r = 0; r < 4; r++) {
        float s = 0.f;
#pragma unroll
        for (int j = 0; j < 4; j++) { float v = acc[i][j][r]; s += v * v; }
#pragma unroll
        for (int m = 1; m < 16; m <<= 1) s += __shfl_xor(s, m);
        if (l16 == 0) ssbuf[waveRow + i * 16 + quad * 4 + r][wave & 1] = s;
      }
    }
    __syncthreads();
#pragma unroll
    for (int i = 0; i < 4; i++)
#pragma unroll
      for (int r = 0; r < 4; r++) {
        int row = waveRow + i * 16 + quad * 4 + r;
        scl[i][r] = rsqrtf(128.0f * (ssbuf[row][0] + ssbuf[row][1]));
      }
  }

#pragma unroll
  for (int i = 0; i < 4; i++) {
#pragma unroll
    for (int j = 0; j < 4; j++) {
      long row0 = rowBase + waveRow + i * 16 + quad * 4;
      long col = colBase + waveCol + j * 16 + l16;
#pragma unroll
      for (int r = 0; r < 4; r++) {
        float v = acc[i][j][r] * scl[i][r];
        long off = (row0 + r) * (long)N + col;
        if (EPI == 0) ((float*)C)[off] = v;
        else          ((u16*)C)[off] = f2bf(v);
      }
    }
  }
}

// ---------------- fp32 -> bf16 cast (vectorized x4) ----------------
__global__ __launch_bounds__(256) void cast_f2b(const float* __restrict__ in,
                                                u16* __restrict__ out, int n4) {
  int i = blockIdx.x * 256 + threadIdx.x;
  if (i >= n4) return;
  float4 v = ((const float4*)in)[i];
  ushort4 u;
  u.x = f2bf(v.x); u.y = f2bf(v.y); u.z = f2bf(v.z); u.w = f2bf(v.w);
  ((ushort4*)out)[i] = u;
}

// ---------------- packed-rDFT matrices (bf16) ----------------
__global__ __launch_bounds__(256) void init_mats(u16* __restrict__ CSp,
                                                 u16* __restrict__ W2pT) {
  int idx = blockIdx.x * 256 + threadIdx.x;  // [0, 32768)
  const float PI64 = 3.14159265358979323846f / 64.0f;
  if (idx < 16384) {
    int p = idx >> 7, n = idx & 127;
    int k = p >> 1;
    float v;
    if (p == 1) v = (n & 1) ? -1.f : 1.f;
    else {
      int t = (k * n) & 127;
      float ang = (float)t * PI64;
      v = (p & 1) ? -sinf(ang) : cosf(ang);
    }
    CSp[p * 128 + n] = f2bf(v);
  } else {
    int r = idx - 16384;
    int p = r >> 7, d = r & 127;
    int k = p >> 1;
    float v;
    if (p == 0) v = 1.0f / 128.0f;
    else if (p == 1) v = ((d & 1) ? -1.f : 1.f) / 128.0f;
    else {
      int t = (k * d) & 127;
      float ang = (float)t * PI64;
      v = ((p & 1) ? -2.f * sinf(ang) : 2.f * cosf(ang)) / 128.0f;
    }
    W2pT[p * 128 + d] = f2bf(v);
  }
}

// ---------------- freq-domain causal cumsum (chunked scan, packed rows) -----
__global__ __launch_bounds__(64) void scan_chunksum(const u16* __restrict__ F,
                                                    float* __restrict__ part) {
  int blk = blockIdx.x;          // bh*64 + c
  int c = blk & 63, bh = blk >> 6;
  int h = bh & 15, b = bh >> 4;
  int l = threadIdx.x;           // 0..63
  float s0 = 0.f, s1 = 0.f;
  for (int t = c * 64; t < c * 64 + 64; ++t) {
    u32 u = ((const u32*)(F + ((long)(b * 4096 + t) * 32 + 16 + h) * 128))[l];
    s0 += bf2f((u16)(u & 0xffff));
    s1 += bf2f((u16)(u >> 16));
  }
  float2 w; w.x = s0; w.y = s1;
  ((float2*)part)[(long)blk * 64 + l] = w;
}

__global__ __launch_bounds__(128) void scan_exclusive(float* __restrict__ part) {
  int bh = blockIdx.x;   // 0..63
  int j = threadIdx.x;   // slot 0..127
  float run = 0.f;
  for (int c = 0; c < 64; ++c) {
    long idx = ((long)(bh * 64 + c)) * 128 + j;
    float v = part[idx];
    part[idx] = run;
    run += v;
  }
}

__global__ __launch_bounds__(64) void scan_main(const u16* __restrict__ F,
                                                u16* __restrict__ QV,
                                                const float* __restrict__ part) {
  int blk = blockIdx.x;          // bh*64 + c
  int c = blk & 63, bh = blk >> 6;
  int h = bh & 15, b = bh >> 4;
  int l = threadIdx.x;           // bin l
  float2 cc = ((const float2*)part)[(long)blk * 64 + l];
  float cr = cc.x, ci = cc.y;
  for (int t = c * 64; t < c * 64 + 64; ++t) {
    long m = (long)(b * 4096 + t);
    u32 ku = ((const u32*)(F + (m * 32 + 16 + h) * 128))[l];
    u32 qu = ((const u32*)(F + (m * 32 + h) * 128))[l];
    float kr = bf2f((u16)(ku & 0xffff)), ki = bf2f((u16)(ku >> 16));
    float qr = bf2f((u16)(qu & 0xffff)), qi = bf2f((u16)(qu >> 16));
    cr += kr; ci += ki;
    float vr, vi;
    if (l == 0) { vr = qr * cr; vi = qi * ci; }  // bins 0 and 64: pure real
    else { vr = qr * cr - qi * ci; vi = qr * ci + qi * cr; }
    ((u32*)(QV + (m * 16 + h) * 128))[l] = pack2(vr, vi);
  }
}

extern "C" void kernel_launch(void* const* d_in, const int* in_sizes, int n_in,
                              void* d_out, int out_size, void* d_ws, size_t ws_size,
                              hipStream_t stream) {
  const float* x   = (const float*)d_in[0];
  const float* Wq  = (const float*)d_in[1];
  const float* Wkv = (const float*)d_in[2];
  const float* Wo  = (const float*)d_in[3];
  float* out = (float*)d_out;

  const long M1 = 16384;          // B*S
  const long D = 2048;
  const long R = M1 * 16;         // 262144 head-rows
  const long XE = M1 * D;
  const long WE = D * D;

  char* ws = (char*)d_ws;
  u16* qkh  = (u16*)(ws);                         // 134 MB: GEMM1 out; QV reuses it
  u16* F    = (u16*)(ws + 134217728);             // 134 MB: packed DFT out (2R x 128)
  u16* xb   = (u16*)(ws + 268435456);             // 67 MB
  u16* wqkb = (u16*)(ws + 335544320);             // 16.8 MB: [Wq;Wkv]
  u16* wob  = (u16*)(ws + 352321536);             // 8.4 MB
  u16* wo2  = (u16*)(ws + 360710144);             // 8.4 MB: folded iDFT.Wo
  u16* CSp  = (u16*)(ws + 369098752);             // 32 KB
  u16* W2pT = (u16*)(ws + 369131520);             // 32 KB
  float* part = (float*)(ws + 369164288);         // 2 MB (64*64*128 f32)
  u16* QV = qkh;

  // casts + transform matrices
  cast_f2b<<<(int)(XE / 4 / 256), 256, 0, stream>>>(x, xb, (int)(XE / 4));
  cast_f2b<<<(int)(WE / 4 / 256), 256, 0, stream>>>(Wq, wqkb, (int)(WE / 4));
  cast_f2b<<<(int)(WE / 4 / 256), 256, 0, stream>>>(Wkv, wqkb + WE, (int)(WE / 4));
  cast_f2b<<<(int)(WE / 4 / 256), 256, 0, stream>>>(Wo, wob, (int)(WE / 4));
  init_mats<<<128, 256, 0, stream>>>(CSp, W2pT);

  // fold iDFT into Wo:  Wo2_h = Wo_h @ W2p  (block-diagonal, M=2048,N=2048,K=128)
  gemm_bt<1, true><<<16 * 16, 256, 0, stream>>>(wob, W2pT, wo2, 2048, 2048, 128, 2048);

  // qkv = x @ [Wq;Wkv]^T, fused per-head normalize (M=16384,N=4096,K=2048)
  gemm256<2><<<(int)((M1 / 256) * (4096 / 256)), 512, 0, stream>>>(
      xb, wqkb, qkh, 4096, (int)D);

  // packed rDFT: F = qkv_rows @ CSp^T  (M=2R, N=128, K=128)
  gemm_bt<1, false><<<(int)(2 * R / 128), 256, 0, stream>>>(
      qkh, CSp, F, (int)(2 * R), 128, 128, 128);

  // chunked causal cumsum + complex multiply -> QV (packed, into qkh)
  scan_chunksum<<<64 * 64, 64, 0, stream>>>(F, part);
  scan_exclusive<<<64, 128, 0, stream>>>(part);
  scan_main<<<64 * 64, 64, 0, stream>>>(F, QV, part);

  // out = QV_flat @ Wo2^T  (fp32 out, M=16384,N=2048,K=2048; iDFT folded in)
  gemm256<0><<<(int)((M1 / 256) * (D / 256)), 512, 0, stream>>>(
      QV, wo2, out, (int)D, (int)D);
}